// Round 10
// baseline (316.517 us; speedup 1.0000x reference)
//
#include <hip/hip_runtime.h>
#include <math.h>

#define N_IMG 4096
#define NBC   1024        // cols per block (256 threads x 4 cols)
#define H_OUT 32          // harris output rows per block
#define HR    38          // H_OUT + 6 halo
#define NMS_HOUT 16       // nms output rows per block (1024 blocks = 4/CU)
#define NMS_HR   22
#define NPIX  (N_IMG * N_IMG)
#define HBLK  1024        // hist kernel grid
#define NREP  8           // histogram replicas (kills merge-atomic serialization)

struct W7 { float w[7]; };

__device__ __forceinline__ unsigned f2k(float f) {
    unsigned u = __float_as_uint(f);
    return (u & 0x80000000u) ? ~u : (u | 0x80000000u);
}
__device__ __forceinline__ float k2f(unsigned k) {
    unsigned u = (k & 0x80000000u) ? (k & 0x7fffffffu) : ~k;
    return __uint_as_float(u);
}

// ---------- per-block radix-select re-derivation over NREP replicas ----------
// Replica layouts: g0r[NREP][4096], g1r[NREP][2][4096], g2r[NREP][2][256].
// Consumers sum replicas -> identical totals as unreplicated (deterministic).
struct SelState { unsigned p1, p2, r1, r2; };

template<int BINS>
__device__ void locate_pair(const unsigned* h0, const unsigned* h1,
                            int repstride, int shift, SelState& s)
{
    __shared__ unsigned scan[256];
    __shared__ unsigned resb[2], resr[2];
    const int tid = threadIdx.x;
    constexpr int per = BINS / 256;
    const bool same = (h0 == h1);

    for (int q = 0; q < 2; q++) {
        if (q == 1 && same) break;
        const unsigned* h = q ? h1 : h0;
        const int base = tid * per;
        unsigned loc[per];
        unsigned sum = 0;
        #pragma unroll
        for (int i = 0; i < per; i++) {
            unsigned c = 0;
            #pragma unroll
            for (int r = 0; r < NREP; r++) c += h[r * repstride + base + i];
            loc[i] = c; sum += c;
        }
        __syncthreads();                  // protect scan[] reuse across calls
        scan[tid] = sum;
        __syncthreads();
        unsigned v = sum;
        #pragma unroll
        for (int off = 1; off < 256; off <<= 1) {
            unsigned t = (tid >= off) ? scan[tid - off] : 0u;
            __syncthreads();
            v += t;
            scan[tid] = v;
            __syncthreads();
        }
        const unsigned excl = v - sum;
        #pragma unroll
        for (int w = 0; w < 2; w++) {
            const unsigned rank = w ? s.r2 : s.r1;
            const bool mine = w ? (same || q == 1) : (q == 0);
            if (mine && rank >= excl && rank < v) {
                unsigned rr = rank - excl;
                #pragma unroll
                for (int i = 0; i < per; i++) {
                    unsigned c = loc[i];
                    if (rr < c) { resb[w] = (unsigned)(base + i); resr[w] = rr; break; }
                    rr -= c;
                }
            }
        }
        __syncthreads();
    }
    s.p1 |= resb[0] << shift; s.r1 = resr[0];
    s.p2 |= resb[1] << shift; s.r2 = resr[1];
}

__device__ __forceinline__ SelState derive0(const unsigned* g0r) {
    SelState s; s.p1 = 0u; s.p2 = 0u;
    s.r1 = (unsigned)(NPIX / 2 - 1); s.r2 = (unsigned)(NPIX / 2);
    locate_pair<4096>(g0r, g0r, 4096, 20, s);
    return s;
}
__device__ __forceinline__ void derive1(const unsigned* g1r, SelState& s) {
    const unsigned* h1 = (s.p1 != s.p2) ? (g1r + 4096) : g1r;
    locate_pair<4096>(g1r, h1, 8192, 8, s);
}
__device__ __forceinline__ void derive2(const unsigned* g2r, SelState& s) {
    const unsigned* h1 = (s.p1 != s.p2) ? (g2r + 256) : g2r;
    locate_pair<256>(g2r, h1, 512, 0, s);
}

// ---------- harris (round-5 body; merge -> replica (bx+by)&7) ----------
__global__ __launch_bounds__(256, 2) void harris_kernel(const float* __restrict__ x,
                                                        float* __restrict__ R,
                                                        unsigned* __restrict__ g0,
                                                        W7 wp)
{
    __shared__ unsigned histo[4096];
    const int tid = threadIdx.x;
    for (int i = tid; i < 4096; i += 256) histo[i] = 0;
    __syncthreads();

    const int row0 = blockIdx.y * H_OUT;
    const int jc   = blockIdx.x * NBC + tid * 4;   // first owned column
    const float* w = wp.w;
    const bool edge = (jc < 4) || (jc >= N_IMG - 8);   // lanes needing col clamps

    float xm[12], xc[12], xp[12];                  // rolling x rows (cols jc-4..jc+7)
    float axx[7][4], ayy[7][4], axy[7][4];         // 7 pending vertical accumulators

    #pragma unroll
    for (int m = 0; m < 7; m++)
        #pragma unroll
        for (int o = 0; o < 4; o++) { axx[m][o] = 0.f; ayy[m][o] = 0.f; axy[m][o] = 0.f; }

    auto loadrow = [&](int ri, float* d) {
        if ((unsigned)ri < N_IMG) {
            const float* p = x + (size_t)ri * N_IMG;
            float4 v0 = make_float4(0.f,0.f,0.f,0.f), v2 = make_float4(0.f,0.f,0.f,0.f);
            if (jc >= 4) v0 = *(const float4*)(p + jc - 4);
            float4 v1 = *(const float4*)(p + jc);
            if (jc + 4 < N_IMG) v2 = *(const float4*)(p + jc + 4);
            d[0]=v0.x; d[1]=v0.y; d[2]=v0.z; d[3]=v0.w;
            d[4]=v1.x; d[5]=v1.y; d[6]=v1.z; d[7]=v1.w;
            d[8]=v2.x; d[9]=v2.y; d[10]=v2.z; d[11]=v2.w;
        } else {
            #pragma unroll
            for (int t = 0; t < 12; t++) d[t] = 0.f;
        }
    };

    loadrow(row0 - 4, xm);
    loadrow(row0 - 3, xc);

    int curb = -1; unsigned cnt = 0;   // histogram run-length state

    auto step = [&](int r, int k, int dmin, bool emit) {
        const int ri = row0 + r - 3;   // image row of this h row
        loadrow(ri + 1, xp);

        if ((unsigned)ri < N_IMG) {
            float dc[12], rd[12];
            #pragma unroll
            for (int t = 0; t < 12; t++) {
                dc[t] = xm[t] + 2.f * xc[t] + xp[t];
                rd[t] = xp[t] - xm[t];
            }
            float ixv[10], iyv[10];
            #pragma unroll
            for (int t = 0; t < 10; t++) {
                ixv[t] = dc[t+2] - dc[t];
                iyv[t] = rd[t] + 2.f * rd[t+1] + rd[t+2];
            }
            if (edge) {                 // execz-skipped by interior waves
                #pragma unroll
                for (int t = 0; t < 10; t++)
                    if ((unsigned)(jc - 3 + t) >= N_IMG) { ixv[t] = 0.f; iyv[t] = 0.f; }
            }
            float sxx[4] = {0,0,0,0}, syy[4] = {0,0,0,0}, sxy[4] = {0,0,0,0};
            #pragma unroll
            for (int t = 0; t < 10; t++) {
                float ix = ixv[t], iy = iyv[t];
                float xx = ix*ix, yy = iy*iy, xy = ix*iy;
                #pragma unroll
                for (int o = 0; o < 4; o++) {
                    const int v = t - o;
                    if (v >= 0 && v < 7) {
                        sxx[o] = fmaf(w[v], xx, sxx[o]);
                        syy[o] = fmaf(w[v], yy, syy[o]);
                        sxy[o] = fmaf(w[v], xy, sxy[o]);
                    }
                }
            }
            #pragma unroll
            for (int d = 0; d < 7; d++) {
                if (d >= dmin) {
                    const int m = (k + d) % 7;   // static after unroll
                    #pragma unroll
                    for (int o = 0; o < 4; o++) {
                        axx[m][o] = fmaf(w[6-d], sxx[o], axx[m][o]);
                        ayy[m][o] = fmaf(w[6-d], syy[o], ayy[m][o]);
                        axy[m][o] = fmaf(w[6-d], sxy[o], axy[m][o]);
                    }
                }
            }
        }

        if (emit) {                     // output q == r completes in slot k
            float4 h;
            float* hp = &h.x;
            #pragma unroll
            for (int o = 0; o < 4; o++) {
                float ax = axx[k][o], ay = ayy[k][o], az = axy[k][o];
                axx[k][o] = 0.f; ayy[k][o] = 0.f; axy[k][o] = 0.f;
                float tr = ax + ay;
                hp[o] = ax*ay - az*az - 0.05f*tr*tr;
            }
            const int orow = row0 + r - 6;
            *(float4*)(R + (size_t)orow * N_IMG + jc) = h;
            #pragma unroll
            for (int o = 0; o < 4; o++) {
                int b = (int)(f2k(hp[o]) >> 20);
                if (b == curb) cnt++;
                else { if (curb >= 0) atomicAdd(&histo[curb], cnt); curb = b; cnt = 1; }
            }
        }
        #pragma unroll
        for (int t = 0; t < 12; t++) { xm[t] = xc[t]; xc[t] = xp[t]; }
    };

    #pragma unroll
    for (int rr = 0; rr < 7; ++rr)
        step(rr, rr, 6 - rr, rr == 6);
    for (int it = 1; it < 6; ++it) {
        #pragma unroll
        for (int k = 0; k < 7; ++k) {
            const int r = it * 7 + k;
            if (r < HR) step(r, k, 0, true);
        }
    }

    if (curb >= 0) atomicAdd(&histo[curb], cnt);
    __syncthreads();
    unsigned* gdst = g0 + ((blockIdx.x + blockIdx.y) & (NREP - 1)) * 4096;
    for (int i = tid; i < 4096; i += 256) {
        unsigned c = histo[i];
        if (c) atomicAdd(&gdst[i], c);
    }
}

// ---------- level-1 histogram (4-deep batches; merge -> replica bx&7) ----------
__global__ __launch_bounds__(256) void hist1_kernel(const float* __restrict__ R,
                                                    const unsigned* __restrict__ g0,
                                                    unsigned* __restrict__ g1)
{
    __shared__ unsigned h[2][4096];
    const int tid = threadIdx.x;
    for (int i = tid; i < 8192; i += 256) ((unsigned*)h)[i] = 0u;

    SelState s = derive0(g0);            // internal barriers also cover h zero-init
    const unsigned p1 = s.p1, p2 = s.p2;
    const bool dual = (p1 != p2);
    const unsigned mask = 0xFFF00000u;
    const int shift = 8;

    const int n4 = NPIX / 4;
    const int stride = gridDim.x * 256;
    int curb1 = -1; unsigned cnt1 = 0;
    int curb2 = -1; unsigned cnt2 = 0;
    const float4* R4 = (const float4*)R;

    auto proc = [&](unsigned k) {
        if ((k & mask) == p1) {
            int b = (int)((k >> shift) & 4095u);
            if (b == curb1) cnt1++;
            else { if (cnt1) atomicAdd(&h[0][curb1], cnt1); curb1 = b; cnt1 = 1; }
        }
        if (dual && (k & mask) == p2) {
            int b = (int)((k >> shift) & 4095u);
            if (b == curb2) cnt2++;
            else { if (cnt2) atomicAdd(&h[1][curb2], cnt2); curb2 = b; cnt2 = 1; }
        }
    };

    int i = blockIdx.x * 256 + tid;
    for (; i + 3 * stride < n4; i += 4 * stride) {
        float4 va = R4[i];                 // four independent loads in flight
        float4 vb = R4[i + stride];
        float4 vc = R4[i + 2 * stride];
        float4 vd = R4[i + 3 * stride];
        float vv[16] = {va.x, va.y, va.z, va.w, vb.x, vb.y, vb.z, vb.w,
                        vc.x, vc.y, vc.z, vc.w, vd.x, vd.y, vd.z, vd.w};
        #pragma unroll
        for (int t = 0; t < 16; t++) proc(f2k(vv[t]));
    }
    for (; i < n4; i += stride) {          // tail
        float4 va = R4[i];
        float vv[4] = {va.x, va.y, va.z, va.w};
        #pragma unroll
        for (int t = 0; t < 4; t++) proc(f2k(vv[t]));
    }
    if (cnt1) atomicAdd(&h[0][curb1], cnt1);
    if (cnt2) atomicAdd(&h[1][curb2], cnt2);
    __syncthreads();
    unsigned* gdst = g1 + (blockIdx.x & (NREP - 1)) * 8192;
    for (int j = tid; j < 4096; j += 256) {
        unsigned c0 = h[0][j]; if (c0) atomicAdd(&gdst[j], c0);
        if (dual) { unsigned c1 = h[1][j]; if (c1) atomicAdd(&gdst[4096 + j], c1); }
    }
}

// ---------- level-2 histogram (4-deep batches; merge -> replica bx&7) ----------
__global__ __launch_bounds__(256) void hist2_kernel(const float* __restrict__ R,
                                                    const unsigned* __restrict__ g0,
                                                    const unsigned* __restrict__ g1,
                                                    unsigned* __restrict__ g2)
{
    __shared__ unsigned h[2][256];
    const int tid = threadIdx.x;
    for (int i = tid; i < 512; i += 256) ((unsigned*)h)[i] = 0u;

    SelState s = derive0(g0);
    derive1(g1, s);
    const unsigned p1 = s.p1, p2 = s.p2;
    const bool dual = (p1 != p2);
    const unsigned mask = 0xFFFFFF00u;

    const int n4 = NPIX / 4;
    const int stride = gridDim.x * 256;
    int curb1 = -1; unsigned cnt1 = 0;
    int curb2 = -1; unsigned cnt2 = 0;
    const float4* R4 = (const float4*)R;

    auto proc = [&](unsigned k) {
        if ((k & mask) == p1) {
            int b = (int)(k & 255u);
            if (b == curb1) cnt1++;
            else { if (cnt1) atomicAdd(&h[0][curb1], cnt1); curb1 = b; cnt1 = 1; }
        }
        if (dual && (k & mask) == p2) {
            int b = (int)(k & 255u);
            if (b == curb2) cnt2++;
            else { if (cnt2) atomicAdd(&h[1][curb2], cnt2); curb2 = b; cnt2 = 1; }
        }
    };

    int i = blockIdx.x * 256 + tid;
    for (; i + 3 * stride < n4; i += 4 * stride) {
        float4 va = R4[i];
        float4 vb = R4[i + stride];
        float4 vc = R4[i + 2 * stride];
        float4 vd = R4[i + 3 * stride];
        float vv[16] = {va.x, va.y, va.z, va.w, vb.x, vb.y, vb.z, vb.w,
                        vc.x, vc.y, vc.z, vc.w, vd.x, vd.y, vd.z, vd.w};
        #pragma unroll
        for (int t = 0; t < 16; t++) proc(f2k(vv[t]));
    }
    for (; i < n4; i += stride) {
        float4 va = R4[i];
        float vv[4] = {va.x, va.y, va.z, va.w};
        #pragma unroll
        for (int t = 0; t < 4; t++) proc(f2k(vv[t]));
    }
    if (cnt1) atomicAdd(&h[0][curb1], cnt1);
    if (cnt2) atomicAdd(&h[1][curb2], cnt2);
    __syncthreads();
    unsigned* gdst = g2 + (blockIdx.x & (NREP - 1)) * 512;
    if (tid < 256) {
        unsigned c0 = h[0][tid]; if (c0) atomicAdd(&gdst[tid], c0);
        if (dual) { unsigned c1 = h[1][tid]; if (c1) atomicAdd(&gdst[256 + tid], c1); }
    }
}

// zero all replica histograms: 8*(4096 + 8192 + 512) = 102400 words
__global__ __launch_bounds__(256) void init_kernel(unsigned* __restrict__ g)
{
    const unsigned n = NREP * (4096u + 8192u + 512u);
    for (unsigned i = blockIdx.x * 256u + threadIdx.x; i < n; i += gridDim.x * 256u)
        g[i] = 0u;
}

// ---------- NMS (round-5 body; H_OUT=16 -> 1024 blocks = 4/CU for latency) ----------
__global__ __launch_bounds__(256, 4) void nms_kernel(const float* __restrict__ R,
                                                     const unsigned* __restrict__ g0,
                                                     const unsigned* __restrict__ g1,
                                                     const unsigned* __restrict__ g2,
                                                     float* __restrict__ out)
{
    const int tid  = threadIdx.x;

    SelState s = derive0(g0);
    derive1(g1, s);
    derive2(g2, s);
    const float med = 0.5f * (k2f(s.p1) + k2f(s.p2));

    const int row0 = blockIdx.y * NMS_HOUT;
    const int jc   = blockIdx.x * NBC + tid * 4;

    float vm[7][4];                    // 7 pending vertical-max accumulators
    float ct[7][4];                    // center-value ring
    #pragma unroll
    for (int m = 0; m < 7; m++)
        #pragma unroll
        for (int o = 0; o < 4; o++) vm[m][o] = -INFINITY;

    auto loadrowT = [&](int ri, float* d) {
        if ((unsigned)ri < N_IMG) {
            const float* p = R + (size_t)ri * N_IMG;
            float4 v1 = *(const float4*)(p + jc);
            d[4] = (v1.x >= med) ? v1.x : 0.f;
            d[5] = (v1.y >= med) ? v1.y : 0.f;
            d[6] = (v1.z >= med) ? v1.z : 0.f;
            d[7] = (v1.w >= med) ? v1.w : 0.f;
            if (jc >= 4) {
                float4 v0 = *(const float4*)(p + jc - 4);
                d[0] = (v0.x >= med) ? v0.x : 0.f;
                d[1] = (v0.y >= med) ? v0.y : 0.f;
                d[2] = (v0.z >= med) ? v0.z : 0.f;
                d[3] = (v0.w >= med) ? v0.w : 0.f;
            } else { d[0]=d[1]=d[2]=d[3] = -INFINITY; }
            if (jc + 4 < N_IMG) {
                float4 v2 = *(const float4*)(p + jc + 4);
                d[8]  = (v2.x >= med) ? v2.x : 0.f;
                d[9]  = (v2.y >= med) ? v2.y : 0.f;
                d[10] = (v2.z >= med) ? v2.z : 0.f;
                d[11] = (v2.w >= med) ? v2.w : 0.f;
            } else { d[8]=d[9]=d[10]=d[11] = -INFINITY; }
        } else {
            #pragma unroll
            for (int t = 0; t < 12; t++) d[t] = -INFINITY;
        }
    };

    auto stepn = [&](int r, int k, int dmin, bool emit) {
        const int ri = row0 + r - 3;
        float a[12];
        loadrowT(ri, a);
        float hm[4];
        #pragma unroll
        for (int o = 0; o < 4; o++) {
            float m01 = fmaxf(a[o+1], a[o+2]);
            float m23 = fmaxf(a[o+3], a[o+4]);
            float m45 = fmaxf(a[o+5], a[o+6]);
            hm[o] = fmaxf(fmaxf(m01, m23), fmaxf(m45, a[o+7]));
            ct[k][o] = a[4+o];
        }
        #pragma unroll
        for (int d = 0; d < 7; d++) {
            if (d >= dmin) {
                const int m = (k + d) % 7;   // static after unroll
                #pragma unroll
                for (int o = 0; o < 4; o++)
                    vm[m][o] = fmaxf(vm[m][o], hm[o]);
            }
        }
        if (emit) {
            float4 ov;
            float* op = &ov.x;
            #pragma unroll
            for (int o = 0; o < 4; o++) {
                float m = vm[k][o];
                vm[k][o] = -INFINITY;
                float c = ct[(k+4) % 7][o];
                op[o] = (c != m) ? 0.f : m;
            }
            const int orow = row0 + r - 6;
            *(float4*)(out + (size_t)orow * N_IMG + jc) = ov;
        }
    };

    #pragma unroll
    for (int rr = 0; rr < 7; ++rr)
        stepn(rr, rr, 6 - rr, rr == 6);
    for (int it = 1; it < 4; ++it) {
        #pragma unroll
        for (int k = 0; k < 7; ++k) {
            const int r = it * 7 + k;
            if (r < NMS_HR) stepn(r, k, 0, true);
        }
    }
}

extern "C" void kernel_launch(void* const* d_in, const int* in_sizes, int n_in,
                              void* d_out, int out_size, void* d_ws, size_t ws_size,
                              hipStream_t stream)
{
    const float* x = (const float*)d_in[0];
    float* R = (float*)d_ws;                                   // 64 MiB
    unsigned* g0 = (unsigned*)((char*)d_ws + (size_t)NPIX * 4); // [8][4096]
    unsigned* g1 = g0 + NREP * 4096;                            // [8][2][4096]
    unsigned* g2 = g1 + NREP * 8192;                            // [8][2][256]
    float* out = (float*)d_out;

    W7 wp;
    {
        double g[7], sm = 0.0;
        for (int i = 0; i < 7; i++) { double ax = (double)i - 3.0; g[i] = exp(-(ax*ax)/50.0); sm += g[i]; }
        for (int i = 0; i < 7; i++) wp.w[i] = (float)(g[i] / sm);
    }

    dim3 sgrid(N_IMG / NBC, N_IMG / H_OUT);       // (4, 128)
    dim3 ngrid(N_IMG / NBC, N_IMG / NMS_HOUT);    // (4, 256)

    init_kernel<<<64, 256, 0, stream>>>(g0);
    harris_kernel<<<sgrid, 256, 0, stream>>>(x, R, g0, wp);        // + level-0 hist
    hist1_kernel<<<HBLK, 256, 0, stream>>>(R, g0, g1);             // derives sel0
    hist2_kernel<<<HBLK, 256, 0, stream>>>(R, g0, g1, g2);         // derives sel0+sel1
    nms_kernel<<<ngrid, 256, 0, stream>>>(R, g0, g1, g2, out);     // derives sel0..2 -> median
}

// Round 11
// 269.531 us; speedup vs baseline: 1.1743x; 1.1743x over previous
//
#include <hip/hip_runtime.h>
#include <math.h>

#define N_IMG 4096
#define NBC   1024        // cols per block (256 threads x 4 cols)
#define H_OUT 32          // output rows per block
#define HR    38          // processed rows per block (H_OUT + 6 halo)
#define NPIX  (N_IMG * N_IMG)
#define HBLK  1024        // hist kernel grid (round-9 proven)

struct W7 { float w[7]; };

__device__ __forceinline__ unsigned f2k(float f) {
    unsigned u = __float_as_uint(f);
    return (u & 0x80000000u) ? ~u : (u | 0x80000000u);
}
__device__ __forceinline__ float k2f(unsigned k) {
    unsigned u = (k & 0x80000000u) ? (k & 0x7fffffffu) : ~k;
    return __uint_as_float(u);
}

// ---------- per-block radix-select re-derivation (no fences, no gates) ----------
struct SelState { unsigned p1, p2, r1, r2; };

template<int BINS>
__device__ void locate_pair(const unsigned* h0, const unsigned* h1,
                            int shift, SelState& s)
{
    __shared__ unsigned scan[256];
    __shared__ unsigned resb[2], resr[2];
    const int tid = threadIdx.x;
    const int per = BINS / 256;
    const bool same = (h0 == h1);

    for (int q = 0; q < 2; q++) {
        if (q == 1 && same) break;
        const unsigned* h = q ? h1 : h0;
        const int base = tid * per;
        unsigned sum = 0;
        #pragma unroll
        for (int i = 0; i < per; i++) sum += h[base + i];
        __syncthreads();                  // protect scan[] reuse across calls
        scan[tid] = sum;
        __syncthreads();
        unsigned v = sum;
        #pragma unroll
        for (int off = 1; off < 256; off <<= 1) {
            unsigned t = (tid >= off) ? scan[tid - off] : 0u;
            __syncthreads();
            v += t;
            scan[tid] = v;
            __syncthreads();
        }
        const unsigned excl = v - sum;
        #pragma unroll
        for (int w = 0; w < 2; w++) {
            const unsigned rank = w ? s.r2 : s.r1;
            const bool mine = w ? (same || q == 1) : (q == 0);
            if (mine && rank >= excl && rank < v) {
                unsigned rr = rank - excl;
                for (int i = 0; i < per; i++) {
                    unsigned c = h[base + i];
                    if (rr < c) { resb[w] = (unsigned)(base + i); resr[w] = rr; break; }
                    rr -= c;
                }
            }
        }
        __syncthreads();
    }
    s.p1 |= resb[0] << shift; s.r1 = resr[0];
    s.p2 |= resb[1] << shift; s.r2 = resr[1];
}

__device__ __forceinline__ SelState derive0(const unsigned* g0) {
    SelState s; s.p1 = 0u; s.p2 = 0u;
    s.r1 = (unsigned)(NPIX / 2 - 1); s.r2 = (unsigned)(NPIX / 2);
    locate_pair<4096>(g0, g0, 20, s);
    return s;
}
__device__ __forceinline__ void derive1(const unsigned* g1, SelState& s) {
    const unsigned* h1 = (s.p1 != s.p2) ? (g1 + 4096) : g1;
    locate_pair<4096>(g1, h1, 8, s);
}
__device__ __forceinline__ void derive2(const unsigned* g2, SelState& s) {
    const unsigned* h1 = (s.p1 != s.p2) ? (g2 + 256) : g2;
    locate_pair<256>(g2, h1, 0, s);
}

// ---------- harris (round-5 body + ISOLATED depth-1 row prefetch) ----------
// The only change vs round 9: loadrow for step r+1 issues at the top of step r
// (xn buffer), so the ~900cy HBM load latency hides under step r's compute
// instead of stalling at the immediate dc/rd use.
__global__ __launch_bounds__(256, 2) void harris_kernel(const float* __restrict__ x,
                                                        float* __restrict__ R,
                                                        unsigned* __restrict__ g0,
                                                        W7 wp)
{
    __shared__ unsigned histo[4096];
    const int tid = threadIdx.x;
    for (int i = tid; i < 4096; i += 256) histo[i] = 0;
    __syncthreads();

    const int row0 = blockIdx.y * H_OUT;
    const int jc   = blockIdx.x * NBC + tid * 4;   // first owned column
    const float* w = wp.w;
    const bool edge = (jc < 4) || (jc >= N_IMG - 8);   // lanes needing col clamps

    float xm[12], xc[12], xp[12], xn[12];          // rolling x rows (cols jc-4..jc+7)
    float axx[7][4], ayy[7][4], axy[7][4];         // 7 pending vertical accumulators

    #pragma unroll
    for (int m = 0; m < 7; m++)
        #pragma unroll
        for (int o = 0; o < 4; o++) { axx[m][o] = 0.f; ayy[m][o] = 0.f; axy[m][o] = 0.f; }

    auto loadrow = [&](int ri, float* d) {
        if ((unsigned)ri < N_IMG) {
            const float* p = x + (size_t)ri * N_IMG;
            float4 v0 = make_float4(0.f,0.f,0.f,0.f), v2 = make_float4(0.f,0.f,0.f,0.f);
            if (jc >= 4) v0 = *(const float4*)(p + jc - 4);
            float4 v1 = *(const float4*)(p + jc);
            if (jc + 4 < N_IMG) v2 = *(const float4*)(p + jc + 4);
            d[0]=v0.x; d[1]=v0.y; d[2]=v0.z; d[3]=v0.w;
            d[4]=v1.x; d[5]=v1.y; d[6]=v1.z; d[7]=v1.w;
            d[8]=v2.x; d[9]=v2.y; d[10]=v2.z; d[11]=v2.w;
        } else {
            #pragma unroll
            for (int t = 0; t < 12; t++) d[t] = 0.f;
        }
    };

    loadrow(row0 - 4, xm);
    loadrow(row0 - 3, xc);
    loadrow(row0 - 2, xp);

    int curb = -1; unsigned cnt = 0;   // histogram run-length state

    auto step = [&](int r, int k, int dmin, bool emit) {
        const int ri = row0 + r - 3;   // image row of this h row
        loadrow(ri + 2, xn);           // PREFETCH: consumed next step (becomes xp)

        if ((unsigned)ri < N_IMG) {
            float dc[12], rd[12];
            #pragma unroll
            for (int t = 0; t < 12; t++) {
                dc[t] = xm[t] + 2.f * xc[t] + xp[t];
                rd[t] = xp[t] - xm[t];
            }
            float ixv[10], iyv[10];
            #pragma unroll
            for (int t = 0; t < 10; t++) {
                ixv[t] = dc[t+2] - dc[t];
                iyv[t] = rd[t] + 2.f * rd[t+1] + rd[t+2];
            }
            if (edge) {                 // execz-skipped by interior waves
                #pragma unroll
                for (int t = 0; t < 10; t++)
                    if ((unsigned)(jc - 3 + t) >= N_IMG) { ixv[t] = 0.f; iyv[t] = 0.f; }
            }
            float sxx[4] = {0,0,0,0}, syy[4] = {0,0,0,0}, sxy[4] = {0,0,0,0};
            #pragma unroll
            for (int t = 0; t < 10; t++) {
                float ix = ixv[t], iy = iyv[t];
                float xx = ix*ix, yy = iy*iy, xy = ix*iy;
                #pragma unroll
                for (int o = 0; o < 4; o++) {
                    const int v = t - o;
                    if (v >= 0 && v < 7) {
                        sxx[o] = fmaf(w[v], xx, sxx[o]);
                        syy[o] = fmaf(w[v], yy, syy[o]);
                        sxy[o] = fmaf(w[v], xy, sxy[o]);
                    }
                }
            }
            #pragma unroll
            for (int d = 0; d < 7; d++) {
                if (d >= dmin) {
                    const int m = (k + d) % 7;   // static after unroll
                    #pragma unroll
                    for (int o = 0; o < 4; o++) {
                        axx[m][o] = fmaf(w[6-d], sxx[o], axx[m][o]);
                        ayy[m][o] = fmaf(w[6-d], syy[o], ayy[m][o]);
                        axy[m][o] = fmaf(w[6-d], sxy[o], axy[m][o]);
                    }
                }
            }
        }

        if (emit) {                     // output q == r completes in slot k
            float4 h;
            float* hp = &h.x;
            #pragma unroll
            for (int o = 0; o < 4; o++) {
                float ax = axx[k][o], ay = ayy[k][o], az = axy[k][o];
                axx[k][o] = 0.f; ayy[k][o] = 0.f; axy[k][o] = 0.f;
                float tr = ax + ay;
                hp[o] = ax*ay - az*az - 0.05f*tr*tr;
            }
            const int orow = row0 + r - 6;
            *(float4*)(R + (size_t)orow * N_IMG + jc) = h;
            #pragma unroll
            for (int o = 0; o < 4; o++) {
                int b = (int)(f2k(hp[o]) >> 20);
                if (b == curb) cnt++;
                else { if (curb >= 0) atomicAdd(&histo[curb], cnt); curb = b; cnt = 1; }
            }
        }
        #pragma unroll
        for (int t = 0; t < 12; t++) { xm[t] = xc[t]; xc[t] = xp[t]; xp[t] = xn[t]; }
    };

    #pragma unroll
    for (int rr = 0; rr < 7; ++rr)
        step(rr, rr, 6 - rr, rr == 6);
    for (int it = 1; it < 6; ++it) {
        #pragma unroll
        for (int k = 0; k < 7; ++k) {
            const int r = it * 7 + k;
            if (r < HR) step(r, k, 0, true);
        }
    }

    if (curb >= 0) atomicAdd(&histo[curb], cnt);
    __syncthreads();
    for (int i = tid; i < 4096; i += 256) {
        unsigned c = histo[i];
        if (c) atomicAdd(&g0[i], c);
    }
}

// ---------- level-1 histogram (EXACT round-9 body) ----------
__global__ __launch_bounds__(256) void hist1_kernel(const float* __restrict__ R,
                                                    const unsigned* __restrict__ g0,
                                                    unsigned* __restrict__ g1)
{
    __shared__ unsigned h[2][4096];
    const int tid = threadIdx.x;
    for (int i = tid; i < 8192; i += 256) ((unsigned*)h)[i] = 0u;

    SelState s = derive0(g0);            // internal barriers also cover h zero-init
    const unsigned p1 = s.p1, p2 = s.p2;
    const bool dual = (p1 != p2);
    const unsigned mask = 0xFFF00000u;
    const int shift = 8;

    const int n4 = NPIX / 4;
    const int stride = gridDim.x * 256;  // 262144 with HBLK=1024
    int curb1 = -1; unsigned cnt1 = 0;
    int curb2 = -1; unsigned cnt2 = 0;
    const float4* R4 = (const float4*)R;

    auto proc = [&](unsigned k) {
        if ((k & mask) == p1) {
            int b = (int)((k >> shift) & 4095u);
            if (b == curb1) cnt1++;
            else { if (cnt1) atomicAdd(&h[0][curb1], cnt1); curb1 = b; cnt1 = 1; }
        }
        if (dual && (k & mask) == p2) {
            int b = (int)((k >> shift) & 4095u);
            if (b == curb2) cnt2++;
            else { if (cnt2) atomicAdd(&h[1][curb2], cnt2); curb2 = b; cnt2 = 1; }
        }
    };

    int i = blockIdx.x * 256 + tid;
    for (; i + 3 * stride < n4; i += 4 * stride) {
        float4 va = R4[i];                 // four independent loads in flight
        float4 vb = R4[i + stride];
        float4 vc = R4[i + 2 * stride];
        float4 vd = R4[i + 3 * stride];
        float vv[16] = {va.x, va.y, va.z, va.w, vb.x, vb.y, vb.z, vb.w,
                        vc.x, vc.y, vc.z, vc.w, vd.x, vd.y, vd.z, vd.w};
        #pragma unroll
        for (int t = 0; t < 16; t++) proc(f2k(vv[t]));
    }
    for (; i < n4; i += stride) {          // tail
        float4 va = R4[i];
        float vv[4] = {va.x, va.y, va.z, va.w};
        #pragma unroll
        for (int t = 0; t < 4; t++) proc(f2k(vv[t]));
    }
    if (cnt1) atomicAdd(&h[0][curb1], cnt1);
    if (cnt2) atomicAdd(&h[1][curb2], cnt2);
    __syncthreads();
    for (int j = tid; j < 4096; j += 256) {
        unsigned c0 = h[0][j]; if (c0) atomicAdd(&g1[j], c0);
        if (dual) { unsigned c1 = h[1][j]; if (c1) atomicAdd(&g1[4096 + j], c1); }
    }
}

// ---------- level-2 histogram (EXACT round-9 body) ----------
__global__ __launch_bounds__(256) void hist2_kernel(const float* __restrict__ R,
                                                    const unsigned* __restrict__ g0,
                                                    const unsigned* __restrict__ g1,
                                                    unsigned* __restrict__ g2)
{
    __shared__ unsigned h[2][256];
    const int tid = threadIdx.x;
    for (int i = tid; i < 512; i += 256) ((unsigned*)h)[i] = 0u;

    SelState s = derive0(g0);
    derive1(g1, s);
    const unsigned p1 = s.p1, p2 = s.p2;
    const bool dual = (p1 != p2);
    const unsigned mask = 0xFFFFFF00u;

    const int n4 = NPIX / 4;
    const int stride = gridDim.x * 256;
    int curb1 = -1; unsigned cnt1 = 0;
    int curb2 = -1; unsigned cnt2 = 0;
    const float4* R4 = (const float4*)R;

    auto proc = [&](unsigned k) {
        if ((k & mask) == p1) {
            int b = (int)(k & 255u);
            if (b == curb1) cnt1++;
            else { if (cnt1) atomicAdd(&h[0][curb1], cnt1); curb1 = b; cnt1 = 1; }
        }
        if (dual && (k & mask) == p2) {
            int b = (int)(k & 255u);
            if (b == curb2) cnt2++;
            else { if (cnt2) atomicAdd(&h[1][curb2], cnt2); curb2 = b; cnt2 = 1; }
        }
    };

    int i = blockIdx.x * 256 + tid;
    for (; i + 3 * stride < n4; i += 4 * stride) {
        float4 va = R4[i];
        float4 vb = R4[i + stride];
        float4 vc = R4[i + 2 * stride];
        float4 vd = R4[i + 3 * stride];
        float vv[16] = {va.x, va.y, va.z, va.w, vb.x, vb.y, vb.z, vb.w,
                        vc.x, vc.y, vc.z, vc.w, vd.x, vd.y, vd.z, vd.w};
        #pragma unroll
        for (int t = 0; t < 16; t++) proc(f2k(vv[t]));
    }
    for (; i < n4; i += stride) {
        float4 va = R4[i];
        float vv[4] = {va.x, va.y, va.z, va.w};
        #pragma unroll
        for (int t = 0; t < 4; t++) proc(f2k(vv[t]));
    }
    if (cnt1) atomicAdd(&h[0][curb1], cnt1);
    if (cnt2) atomicAdd(&h[1][curb2], cnt2);
    __syncthreads();
    if (tid < 256) {
        unsigned c0 = h[0][tid]; if (c0) atomicAdd(&g2[tid], c0);
        if (dual) { unsigned c1 = h[1][tid]; if (c1) atomicAdd(&g2[256 + tid], c1); }
    }
}

__global__ __launch_bounds__(256) void init_kernel(unsigned* __restrict__ g)
{
    const int tid = threadIdx.x;
    for (int i = tid; i < 12800; i += 256) g[i] = 0u;   // g0|g1|g2
}

// ---------- NMS (EXACT round-9/round-5 body) ----------
__global__ __launch_bounds__(256, 2) void nms_kernel(const float* __restrict__ R,
                                                     const unsigned* __restrict__ g0,
                                                     const unsigned* __restrict__ g1,
                                                     const unsigned* __restrict__ g2,
                                                     float* __restrict__ out)
{
    const int tid  = threadIdx.x;

    SelState s = derive0(g0);
    derive1(g1, s);
    derive2(g2, s);
    const float med = 0.5f * (k2f(s.p1) + k2f(s.p2));

    const int row0 = blockIdx.y * H_OUT;
    const int jc   = blockIdx.x * NBC + tid * 4;

    float vm[7][4];                    // 7 pending vertical-max accumulators
    float ct[7][4];                    // center-value ring
    #pragma unroll
    for (int m = 0; m < 7; m++)
        #pragma unroll
        for (int o = 0; o < 4; o++) vm[m][o] = -INFINITY;

    auto loadrowT = [&](int ri, float* d) {
        if ((unsigned)ri < N_IMG) {
            const float* p = R + (size_t)ri * N_IMG;
            float4 v1 = *(const float4*)(p + jc);
            d[4] = (v1.x >= med) ? v1.x : 0.f;
            d[5] = (v1.y >= med) ? v1.y : 0.f;
            d[6] = (v1.z >= med) ? v1.z : 0.f;
            d[7] = (v1.w >= med) ? v1.w : 0.f;
            if (jc >= 4) {
                float4 v0 = *(const float4*)(p + jc - 4);
                d[0] = (v0.x >= med) ? v0.x : 0.f;
                d[1] = (v0.y >= med) ? v0.y : 0.f;
                d[2] = (v0.z >= med) ? v0.z : 0.f;
                d[3] = (v0.w >= med) ? v0.w : 0.f;
            } else { d[0]=d[1]=d[2]=d[3] = -INFINITY; }
            if (jc + 4 < N_IMG) {
                float4 v2 = *(const float4*)(p + jc + 4);
                d[8]  = (v2.x >= med) ? v2.x : 0.f;
                d[9]  = (v2.y >= med) ? v2.y : 0.f;
                d[10] = (v2.z >= med) ? v2.z : 0.f;
                d[11] = (v2.w >= med) ? v2.w : 0.f;
            } else { d[8]=d[9]=d[10]=d[11] = -INFINITY; }
        } else {
            #pragma unroll
            for (int t = 0; t < 12; t++) d[t] = -INFINITY;
        }
    };

    auto stepn = [&](int r, int k, int dmin, bool emit) {
        const int ri = row0 + r - 3;
        float a[12];
        loadrowT(ri, a);
        float hm[4];
        #pragma unroll
        for (int o = 0; o < 4; o++) {
            float m01 = fmaxf(a[o+1], a[o+2]);
            float m23 = fmaxf(a[o+3], a[o+4]);
            float m45 = fmaxf(a[o+5], a[o+6]);
            hm[o] = fmaxf(fmaxf(m01, m23), fmaxf(m45, a[o+7]));
            ct[k][o] = a[4+o];
        }
        #pragma unroll
        for (int d = 0; d < 7; d++) {
            if (d >= dmin) {
                const int m = (k + d) % 7;   // static after unroll
                #pragma unroll
                for (int o = 0; o < 4; o++)
                    vm[m][o] = fmaxf(vm[m][o], hm[o]);
            }
        }
        if (emit) {
            float4 ov;
            float* op = &ov.x;
            #pragma unroll
            for (int o = 0; o < 4; o++) {
                float m = vm[k][o];
                vm[k][o] = -INFINITY;
                float c = ct[(k+4) % 7][o];
                op[o] = (c != m) ? 0.f : m;
            }
            const int orow = row0 + r - 6;
            *(float4*)(out + (size_t)orow * N_IMG + jc) = ov;
        }
    };

    #pragma unroll
    for (int rr = 0; rr < 7; ++rr)
        stepn(rr, rr, 6 - rr, rr == 6);
    for (int it = 1; it < 6; ++it) {
        #pragma unroll
        for (int k = 0; k < 7; ++k) {
            const int r = it * 7 + k;
            if (r < HR) stepn(r, k, 0, true);
        }
    }
}

extern "C" void kernel_launch(void* const* d_in, const int* in_sizes, int n_in,
                              void* d_out, int out_size, void* d_ws, size_t ws_size,
                              hipStream_t stream)
{
    const float* x = (const float*)d_in[0];
    float* R = (float*)d_ws;                                   // 64 MiB
    unsigned* g0 = (unsigned*)((char*)d_ws + (size_t)NPIX * 4);
    unsigned* g1 = g0 + 4096;     // level-1 dual: 2 x 4096
    unsigned* g2 = g1 + 8192;     // level-2 dual: 2 x 256
    float* out = (float*)d_out;

    W7 wp;
    {
        double g[7], sm = 0.0;
        for (int i = 0; i < 7; i++) { double ax = (double)i - 3.0; g[i] = exp(-(ax*ax)/50.0); sm += g[i]; }
        for (int i = 0; i < 7; i++) wp.w[i] = (float)(g[i] / sm);
    }

    dim3 sgrid(N_IMG / NBC, N_IMG / H_OUT);   // (4, 128)

    init_kernel<<<1, 256, 0, stream>>>(g0);
    harris_kernel<<<sgrid, 256, 0, stream>>>(x, R, g0, wp);        // + level-0 hist
    hist1_kernel<<<HBLK, 256, 0, stream>>>(R, g0, g1);             // derives sel0
    hist2_kernel<<<HBLK, 256, 0, stream>>>(R, g0, g1, g2);         // derives sel0+sel1
    nms_kernel<<<sgrid, 256, 0, stream>>>(R, g0, g1, g2, out);     // derives sel0..2 -> median
}

// Round 12
// 262.263 us; speedup vs baseline: 1.2069x; 1.0277x over previous
//
#include <hip/hip_runtime.h>
#include <math.h>

#define N_IMG 4096
#define NBC   1024        // cols per block (256 threads x 4 cols)
#define H_OUT 32          // output rows per block
#define HR    38          // processed rows per block (H_OUT + 6 halo)
#define NPIX  (N_IMG * N_IMG)
#define HBLK  1024        // fallback hist kernel grid (round-9 proven)
#define FINE_WORDS (1u << 20)

struct W7 { float w[7]; };

__device__ __forceinline__ unsigned f2k(float f) {
    unsigned u = __float_as_uint(f);
    return (u & 0x80000000u) ? ~u : (u | 0x80000000u);
}
__device__ __forceinline__ float k2f(unsigned k) {
    unsigned u = (k & 0x80000000u) ? (k & 0x7fffffffu) : ~k;
    return __uint_as_float(u);
}

// ---------- per-block radix-select re-derivation (no fences, no gates) ----------
struct SelState { unsigned p1, p2, r1, r2; };

template<int BINS>
__device__ void locate_pair(const unsigned* h0, const unsigned* h1,
                            int shift, SelState& s)
{
    __shared__ unsigned scan[256];
    __shared__ unsigned resb[2], resr[2];
    const int tid = threadIdx.x;
    const int per = BINS / 256;
    const bool same = (h0 == h1);

    for (int q = 0; q < 2; q++) {
        if (q == 1 && same) break;
        const unsigned* h = q ? h1 : h0;
        const int base = tid * per;
        unsigned sum = 0;
        #pragma unroll
        for (int i = 0; i < per; i++) sum += h[base + i];
        __syncthreads();                  // protect scan[] reuse across calls
        scan[tid] = sum;
        __syncthreads();
        unsigned v = sum;
        #pragma unroll
        for (int off = 1; off < 256; off <<= 1) {
            unsigned t = (tid >= off) ? scan[tid - off] : 0u;
            __syncthreads();
            v += t;
            scan[tid] = v;
            __syncthreads();
        }
        const unsigned excl = v - sum;
        #pragma unroll
        for (int w = 0; w < 2; w++) {
            const unsigned rank = w ? s.r2 : s.r1;
            const bool mine = w ? (same || q == 1) : (q == 0);
            if (mine && rank >= excl && rank < v) {
                unsigned rr = rank - excl;
                for (int i = 0; i < per; i++) {
                    unsigned c = h[base + i];
                    if (rr < c) { resb[w] = (unsigned)(base + i); resr[w] = rr; break; }
                    rr -= c;
                }
            }
        }
        __syncthreads();
    }
    s.p1 |= resb[0] << shift; s.r1 = resr[0];
    s.p2 |= resb[1] << shift; s.r2 = resr[1];
}

__device__ __forceinline__ SelState derive0(const unsigned* g0) {
    SelState s; s.p1 = 0u; s.p2 = 0u;
    s.r1 = (unsigned)(NPIX / 2 - 1); s.r2 = (unsigned)(NPIX / 2);
    locate_pair<4096>(g0, g0, 20, s);
    return s;
}
// fallback (3-pass) derives
__device__ __forceinline__ void derive1(const unsigned* g1, SelState& s) {
    const unsigned* h1 = (s.p1 != s.p2) ? (g1 + 4096) : g1;
    locate_pair<4096>(g1, h1, 8, s);
}
__device__ __forceinline__ void derive2(const unsigned* g2, SelState& s) {
    const unsigned* h1 = (s.p1 != s.p2) ? (g2 + 256) : g2;
    locate_pair<256>(g2, h1, 0, s);
}
// fine-path derives (verified round 6): coarse = bits 19:8, fine window = bits 7:0
__device__ __forceinline__ void derive_coarse(const unsigned* coarse, SelState& s) {
    locate_pair<4096>(coarse, coarse, 8, s);
}
__device__ __forceinline__ void derive_fine(const unsigned* fine, SelState& s) {
    const unsigned* f1 = fine + (((s.p1 >> 8) & 0xFFFu) << 8);
    const unsigned* f2 = fine + (((s.p2 >> 8) & 0xFFFu) << 8);
    locate_pair<256>(f1, f2, 0, s);
}

// ---------- harris (EXACT round-11 body: scatter-acc + depth-1 prefetch) ----------
__global__ __launch_bounds__(256, 2) void harris_kernel(const float* __restrict__ x,
                                                        float* __restrict__ R,
                                                        unsigned* __restrict__ g0,
                                                        W7 wp)
{
    __shared__ unsigned histo[4096];
    const int tid = threadIdx.x;
    for (int i = tid; i < 4096; i += 256) histo[i] = 0;
    __syncthreads();

    const int row0 = blockIdx.y * H_OUT;
    const int jc   = blockIdx.x * NBC + tid * 4;   // first owned column
    const float* w = wp.w;
    const bool edge = (jc < 4) || (jc >= N_IMG - 8);   // lanes needing col clamps

    float xm[12], xc[12], xp[12], xn[12];          // rolling x rows (cols jc-4..jc+7)
    float axx[7][4], ayy[7][4], axy[7][4];         // 7 pending vertical accumulators

    #pragma unroll
    for (int m = 0; m < 7; m++)
        #pragma unroll
        for (int o = 0; o < 4; o++) { axx[m][o] = 0.f; ayy[m][o] = 0.f; axy[m][o] = 0.f; }

    auto loadrow = [&](int ri, float* d) {
        if ((unsigned)ri < N_IMG) {
            const float* p = x + (size_t)ri * N_IMG;
            float4 v0 = make_float4(0.f,0.f,0.f,0.f), v2 = make_float4(0.f,0.f,0.f,0.f);
            if (jc >= 4) v0 = *(const float4*)(p + jc - 4);
            float4 v1 = *(const float4*)(p + jc);
            if (jc + 4 < N_IMG) v2 = *(const float4*)(p + jc + 4);
            d[0]=v0.x; d[1]=v0.y; d[2]=v0.z; d[3]=v0.w;
            d[4]=v1.x; d[5]=v1.y; d[6]=v1.z; d[7]=v1.w;
            d[8]=v2.x; d[9]=v2.y; d[10]=v2.z; d[11]=v2.w;
        } else {
            #pragma unroll
            for (int t = 0; t < 12; t++) d[t] = 0.f;
        }
    };

    loadrow(row0 - 4, xm);
    loadrow(row0 - 3, xc);
    loadrow(row0 - 2, xp);

    int curb = -1; unsigned cnt = 0;   // histogram run-length state

    auto step = [&](int r, int k, int dmin, bool emit) {
        const int ri = row0 + r - 3;   // image row of this h row
        loadrow(ri + 2, xn);           // PREFETCH: consumed next step (becomes xp)

        if ((unsigned)ri < N_IMG) {
            float dc[12], rd[12];
            #pragma unroll
            for (int t = 0; t < 12; t++) {
                dc[t] = xm[t] + 2.f * xc[t] + xp[t];
                rd[t] = xp[t] - xm[t];
            }
            float ixv[10], iyv[10];
            #pragma unroll
            for (int t = 0; t < 10; t++) {
                ixv[t] = dc[t+2] - dc[t];
                iyv[t] = rd[t] + 2.f * rd[t+1] + rd[t+2];
            }
            if (edge) {                 // execz-skipped by interior waves
                #pragma unroll
                for (int t = 0; t < 10; t++)
                    if ((unsigned)(jc - 3 + t) >= N_IMG) { ixv[t] = 0.f; iyv[t] = 0.f; }
            }
            float sxx[4] = {0,0,0,0}, syy[4] = {0,0,0,0}, sxy[4] = {0,0,0,0};
            #pragma unroll
            for (int t = 0; t < 10; t++) {
                float ix = ixv[t], iy = iyv[t];
                float xx = ix*ix, yy = iy*iy, xy = ix*iy;
                #pragma unroll
                for (int o = 0; o < 4; o++) {
                    const int v = t - o;
                    if (v >= 0 && v < 7) {
                        sxx[o] = fmaf(w[v], xx, sxx[o]);
                        syy[o] = fmaf(w[v], yy, syy[o]);
                        sxy[o] = fmaf(w[v], xy, sxy[o]);
                    }
                }
            }
            #pragma unroll
            for (int d = 0; d < 7; d++) {
                if (d >= dmin) {
                    const int m = (k + d) % 7;   // static after unroll
                    #pragma unroll
                    for (int o = 0; o < 4; o++) {
                        axx[m][o] = fmaf(w[6-d], sxx[o], axx[m][o]);
                        ayy[m][o] = fmaf(w[6-d], syy[o], ayy[m][o]);
                        axy[m][o] = fmaf(w[6-d], sxy[o], axy[m][o]);
                    }
                }
            }
        }

        if (emit) {                     // output q == r completes in slot k
            float4 h;
            float* hp = &h.x;
            #pragma unroll
            for (int o = 0; o < 4; o++) {
                float ax = axx[k][o], ay = ayy[k][o], az = axy[k][o];
                axx[k][o] = 0.f; ayy[k][o] = 0.f; axy[k][o] = 0.f;
                float tr = ax + ay;
                hp[o] = ax*ay - az*az - 0.05f*tr*tr;
            }
            const int orow = row0 + r - 6;
            *(float4*)(R + (size_t)orow * N_IMG + jc) = h;
            #pragma unroll
            for (int o = 0; o < 4; o++) {
                int b = (int)(f2k(hp[o]) >> 20);
                if (b == curb) cnt++;
                else { if (curb >= 0) atomicAdd(&histo[curb], cnt); curb = b; cnt = 1; }
            }
        }
        #pragma unroll
        for (int t = 0; t < 12; t++) { xm[t] = xc[t]; xc[t] = xp[t]; xp[t] = xn[t]; }
    };

    #pragma unroll
    for (int rr = 0; rr < 7; ++rr)
        step(rr, rr, 6 - rr, rr == 6);
    for (int it = 1; it < 6; ++it) {
        #pragma unroll
        for (int k = 0; k < 7; ++k) {
            const int r = it * 7 + k;
            if (r < HR) step(r, k, 0, true);
        }
    }

    if (curb >= 0) atomicAdd(&histo[curb], cnt);
    __syncthreads();
    for (int i = tid; i < 4096; i += 256) {
        unsigned c = histo[i];
        if (c) atomicAdd(&g0[i], c);
    }
}

// ---------- FINE PATH: one R scan resolving all 20 remaining bits ----------
// No coarse atomics in the scan (round-7 lesson: p1-bin holds ~8M values ->
// 4096-address chains serialize). Fine bins are ~uniform over 1M addresses.
// Dual case: block-local max/min reduce -> ONE atomic per block.
__global__ __launch_bounds__(256) void histF_kernel(const float* __restrict__ R,
                                                    const unsigned* __restrict__ g0,
                                                    unsigned* __restrict__ fine,
                                                    unsigned* __restrict__ mm)
{
    __shared__ unsigned rmax[256], rmin[256];
    SelState s = derive0(g0);
    const unsigned p1 = s.p1, p2 = s.p2;
    const bool dual = (p1 != p2);
    const unsigned mask = 0xFFF00000u;
    const int tid = threadIdx.x;
    const int n4 = NPIX / 4;
    const float4* R4 = (const float4*)R;

    if (!dual) {
        unsigned curlo = 0xFFFFFFFFu; unsigned cnt = 0;
        for (int i = blockIdx.x * 256 + tid; i < n4; i += gridDim.x * 256) {
            float4 v = R4[i];
            float vv[4] = {v.x, v.y, v.z, v.w};
            #pragma unroll
            for (int t = 0; t < 4; t++) {
                unsigned k = f2k(vv[t]);
                if ((k & mask) == p1) {
                    unsigned lo = k & 0xFFFFFu;
                    if (lo == curlo) cnt++;
                    else { if (cnt) atomicAdd(&fine[curlo], cnt); curlo = lo; cnt = 1; }
                }
            }
        }
        if (cnt) atomicAdd(&fine[curlo], cnt);
    } else {
        // rank N/2-1 = max of bin p1; rank N/2 = min of bin p2
        unsigned bmax = 0u, bmin = 0xFFFFFFFFu;
        for (int i = blockIdx.x * 256 + tid; i < n4; i += gridDim.x * 256) {
            float4 v = R4[i];
            float vv[4] = {v.x, v.y, v.z, v.w};
            #pragma unroll
            for (int t = 0; t < 4; t++) {
                unsigned k = f2k(vv[t]);
                if ((k & mask) == p1) bmax = max(bmax, k);
                if ((k & mask) == p2) bmin = min(bmin, k);
            }
        }
        rmax[tid] = bmax; rmin[tid] = bmin;
        __syncthreads();
        for (int off = 128; off; off >>= 1) {
            if (tid < off) {
                rmax[tid] = max(rmax[tid], rmax[tid + off]);
                rmin[tid] = min(rmin[tid], rmin[tid + off]);
            }
            __syncthreads();
        }
        if (tid == 0) { atomicMax(&mm[0], rmax[0]); atomicMin(&mm[1], rmin[0]); }
    }
}

// coarse[c] = sum of fine[c*256 .. c*256+255]; one wave per coarse bin, no atomics
__global__ __launch_bounds__(256) void build_coarse_kernel(const unsigned* __restrict__ fine,
                                                           unsigned* __restrict__ coarse)
{
    const int tid = threadIdx.x;
    const int wave = tid >> 6, lane = tid & 63;
    const int c = blockIdx.x * 4 + wave;          // 1024 blocks x 4 waves = 4096 bins
    const uint4* f4 = (const uint4*)(fine + (size_t)c * 256);
    uint4 v = f4[lane];
    unsigned sm = v.x + v.y + v.z + v.w;
    #pragma unroll
    for (int off = 32; off; off >>= 1) sm += __shfl_down(sm, off);
    if (lane == 0) coarse[c] = sm;
}

// ---------- FALLBACK PATH (round-9 exact): 3-pass LDS radix ----------
__global__ __launch_bounds__(256) void hist1_kernel(const float* __restrict__ R,
                                                    const unsigned* __restrict__ g0,
                                                    unsigned* __restrict__ g1)
{
    __shared__ unsigned h[2][4096];
    const int tid = threadIdx.x;
    for (int i = tid; i < 8192; i += 256) ((unsigned*)h)[i] = 0u;

    SelState s = derive0(g0);
    const unsigned p1 = s.p1, p2 = s.p2;
    const bool dual = (p1 != p2);
    const unsigned mask = 0xFFF00000u;
    const int shift = 8;

    const int n4 = NPIX / 4;
    const int stride = gridDim.x * 256;
    int curb1 = -1; unsigned cnt1 = 0;
    int curb2 = -1; unsigned cnt2 = 0;
    const float4* R4 = (const float4*)R;

    auto proc = [&](unsigned k) {
        if ((k & mask) == p1) {
            int b = (int)((k >> shift) & 4095u);
            if (b == curb1) cnt1++;
            else { if (cnt1) atomicAdd(&h[0][curb1], cnt1); curb1 = b; cnt1 = 1; }
        }
        if (dual && (k & mask) == p2) {
            int b = (int)((k >> shift) & 4095u);
            if (b == curb2) cnt2++;
            else { if (cnt2) atomicAdd(&h[1][curb2], cnt2); curb2 = b; cnt2 = 1; }
        }
    };

    int i = blockIdx.x * 256 + tid;
    for (; i + 3 * stride < n4; i += 4 * stride) {
        float4 va = R4[i];
        float4 vb = R4[i + stride];
        float4 vc = R4[i + 2 * stride];
        float4 vd = R4[i + 3 * stride];
        float vv[16] = {va.x, va.y, va.z, va.w, vb.x, vb.y, vb.z, vb.w,
                        vc.x, vc.y, vc.z, vc.w, vd.x, vd.y, vd.z, vd.w};
        #pragma unroll
        for (int t = 0; t < 16; t++) proc(f2k(vv[t]));
    }
    for (; i < n4; i += stride) {
        float4 va = R4[i];
        float vv[4] = {va.x, va.y, va.z, va.w};
        #pragma unroll
        for (int t = 0; t < 4; t++) proc(f2k(vv[t]));
    }
    if (cnt1) atomicAdd(&h[0][curb1], cnt1);
    if (cnt2) atomicAdd(&h[1][curb2], cnt2);
    __syncthreads();
    for (int j = tid; j < 4096; j += 256) {
        unsigned c0 = h[0][j]; if (c0) atomicAdd(&g1[j], c0);
        if (dual) { unsigned c1 = h[1][j]; if (c1) atomicAdd(&g1[4096 + j], c1); }
    }
}

__global__ __launch_bounds__(256) void hist2_kernel(const float* __restrict__ R,
                                                    const unsigned* __restrict__ g0,
                                                    const unsigned* __restrict__ g1,
                                                    unsigned* __restrict__ g2)
{
    __shared__ unsigned h[2][256];
    const int tid = threadIdx.x;
    for (int i = tid; i < 512; i += 256) ((unsigned*)h)[i] = 0u;

    SelState s = derive0(g0);
    derive1(g1, s);
    const unsigned p1 = s.p1, p2 = s.p2;
    const bool dual = (p1 != p2);
    const unsigned mask = 0xFFFFFF00u;

    const int n4 = NPIX / 4;
    const int stride = gridDim.x * 256;
    int curb1 = -1; unsigned cnt1 = 0;
    int curb2 = -1; unsigned cnt2 = 0;
    const float4* R4 = (const float4*)R;

    auto proc = [&](unsigned k) {
        if ((k & mask) == p1) {
            int b = (int)(k & 255u);
            if (b == curb1) cnt1++;
            else { if (cnt1) atomicAdd(&h[0][curb1], cnt1); curb1 = b; cnt1 = 1; }
        }
        if (dual && (k & mask) == p2) {
            int b = (int)(k & 255u);
            if (b == curb2) cnt2++;
            else { if (cnt2) atomicAdd(&h[1][curb2], cnt2); curb2 = b; cnt2 = 1; }
        }
    };

    int i = blockIdx.x * 256 + tid;
    for (; i + 3 * stride < n4; i += 4 * stride) {
        float4 va = R4[i];
        float4 vb = R4[i + stride];
        float4 vc = R4[i + 2 * stride];
        float4 vd = R4[i + 3 * stride];
        float vv[16] = {va.x, va.y, va.z, va.w, vb.x, vb.y, vb.z, vb.w,
                        vc.x, vc.y, vc.z, vc.w, vd.x, vd.y, vd.z, vd.w};
        #pragma unroll
        for (int t = 0; t < 16; t++) proc(f2k(vv[t]));
    }
    for (; i < n4; i += stride) {
        float4 va = R4[i];
        float vv[4] = {va.x, va.y, va.z, va.w};
        #pragma unroll
        for (int t = 0; t < 4; t++) proc(f2k(vv[t]));
    }
    if (cnt1) atomicAdd(&h[0][curb1], cnt1);
    if (cnt2) atomicAdd(&h[1][curb2], cnt2);
    __syncthreads();
    if (tid < 256) {
        unsigned c0 = h[0][tid]; if (c0) atomicAdd(&g2[tid], c0);
        if (dual) { unsigned c1 = h[1][tid]; if (c1) atomicAdd(&g2[256 + tid], c1); }
    }
}

// zero nwords at g; set mm sentinels in fine mode
__global__ __launch_bounds__(256) void init_kernel(unsigned* __restrict__ g,
                                                   unsigned nwords,
                                                   unsigned* __restrict__ mm,
                                                   int fine_mode)
{
    for (unsigned i = blockIdx.x * 256u + threadIdx.x; i < nwords; i += gridDim.x * 256u)
        g[i] = 0u;
    if (fine_mode && blockIdx.x == 0 && threadIdx.x == 0) {
        mm[0] = 0u; mm[1] = 0xFFFFFFFFu;
    }
}

// ---------- NMS (round-9 body; mode selects derive chain) ----------
__global__ __launch_bounds__(256, 2) void nms_kernel(const float* __restrict__ R,
                                                     const unsigned* __restrict__ g0,
                                                     const unsigned* __restrict__ g1,
                                                     const unsigned* __restrict__ g2,
                                                     const unsigned* __restrict__ coarse,
                                                     const unsigned* __restrict__ fine,
                                                     const unsigned* __restrict__ mm,
                                                     int mode,
                                                     float* __restrict__ out)
{
    const int tid  = threadIdx.x;

    SelState s = derive0(g0);
    float med;
    if (mode == 1) {
        if (s.p1 != s.p2) {
            med = 0.5f * (k2f(mm[0]) + k2f(mm[1]));
        } else {
            derive_coarse(coarse, s);
            derive_fine(fine, s);
            med = 0.5f * (k2f(s.p1) + k2f(s.p2));
        }
    } else {
        derive1(g1, s);
        derive2(g2, s);
        med = 0.5f * (k2f(s.p1) + k2f(s.p2));
    }

    const int row0 = blockIdx.y * H_OUT;
    const int jc   = blockIdx.x * NBC + tid * 4;

    float vm[7][4];                    // 7 pending vertical-max accumulators
    float ct[7][4];                    // center-value ring
    #pragma unroll
    for (int m = 0; m < 7; m++)
        #pragma unroll
        for (int o = 0; o < 4; o++) vm[m][o] = -INFINITY;

    auto loadrowT = [&](int ri, float* d) {
        if ((unsigned)ri < N_IMG) {
            const float* p = R + (size_t)ri * N_IMG;
            float4 v1 = *(const float4*)(p + jc);
            d[4] = (v1.x >= med) ? v1.x : 0.f;
            d[5] = (v1.y >= med) ? v1.y : 0.f;
            d[6] = (v1.z >= med) ? v1.z : 0.f;
            d[7] = (v1.w >= med) ? v1.w : 0.f;
            if (jc >= 4) {
                float4 v0 = *(const float4*)(p + jc - 4);
                d[0] = (v0.x >= med) ? v0.x : 0.f;
                d[1] = (v0.y >= med) ? v0.y : 0.f;
                d[2] = (v0.z >= med) ? v0.z : 0.f;
                d[3] = (v0.w >= med) ? v0.w : 0.f;
            } else { d[0]=d[1]=d[2]=d[3] = -INFINITY; }
            if (jc + 4 < N_IMG) {
                float4 v2 = *(const float4*)(p + jc + 4);
                d[8]  = (v2.x >= med) ? v2.x : 0.f;
                d[9]  = (v2.y >= med) ? v2.y : 0.f;
                d[10] = (v2.z >= med) ? v2.z : 0.f;
                d[11] = (v2.w >= med) ? v2.w : 0.f;
            } else { d[8]=d[9]=d[10]=d[11] = -INFINITY; }
        } else {
            #pragma unroll
            for (int t = 0; t < 12; t++) d[t] = -INFINITY;
        }
    };

    auto stepn = [&](int r, int k, int dmin, bool emit) {
        const int ri = row0 + r - 3;
        float a[12];
        loadrowT(ri, a);
        float hm[4];
        #pragma unroll
        for (int o = 0; o < 4; o++) {
            float m01 = fmaxf(a[o+1], a[o+2]);
            float m23 = fmaxf(a[o+3], a[o+4]);
            float m45 = fmaxf(a[o+5], a[o+6]);
            hm[o] = fmaxf(fmaxf(m01, m23), fmaxf(m45, a[o+7]));
            ct[k][o] = a[4+o];
        }
        #pragma unroll
        for (int d = 0; d < 7; d++) {
            if (d >= dmin) {
                const int m = (k + d) % 7;   // static after unroll
                #pragma unroll
                for (int o = 0; o < 4; o++)
                    vm[m][o] = fmaxf(vm[m][o], hm[o]);
            }
        }
        if (emit) {
            float4 ov;
            float* op = &ov.x;
            #pragma unroll
            for (int o = 0; o < 4; o++) {
                float m = vm[k][o];
                vm[k][o] = -INFINITY;
                float c = ct[(k+4) % 7][o];
                op[o] = (c != m) ? 0.f : m;
            }
            const int orow = row0 + r - 6;
            *(float4*)(out + (size_t)orow * N_IMG + jc) = ov;
        }
    };

    #pragma unroll
    for (int rr = 0; rr < 7; ++rr)
        stepn(rr, rr, 6 - rr, rr == 6);
    for (int it = 1; it < 6; ++it) {
        #pragma unroll
        for (int k = 0; k < 7; ++k) {
            const int r = it * 7 + k;
            if (r < HR) stepn(r, k, 0, true);
        }
    }
}

extern "C" void kernel_launch(void* const* d_in, const int* in_sizes, int n_in,
                              void* d_out, int out_size, void* d_ws, size_t ws_size,
                              hipStream_t stream)
{
    const float* x = (const float*)d_in[0];
    float* R = (float*)d_ws;                                   // 64 MiB
    unsigned* g0 = (unsigned*)((char*)d_ws + (size_t)NPIX * 4);
    float* out = (float*)d_out;

    W7 wp;
    {
        double g[7], sm = 0.0;
        for (int i = 0; i < 7; i++) { double ax = (double)i - 3.0; g[i] = exp(-(ax*ax)/50.0); sm += g[i]; }
        for (int i = 0; i < 7; i++) wp.w[i] = (float)(g[i] / sm);
    }

    dim3 sgrid(N_IMG / NBC, N_IMG / H_OUT);   // (4, 128)

    // fine layout: g0[4096] | coarse[4096] | mm+pad[64] | fine[1M]
    const unsigned fine_words = 4096u + 4096u + 64u + FINE_WORDS;
    const size_t need_fine = (size_t)NPIX * 4 + (size_t)fine_words * 4;   // == round-6 proven size

    if (ws_size >= need_fine) {
        unsigned* coarse = g0 + 4096;
        unsigned* mm     = coarse + 4096;
        unsigned* fine   = mm + 64;
        init_kernel<<<1024, 256, 0, stream>>>(g0, fine_words, mm, 1);
        harris_kernel<<<sgrid, 256, 0, stream>>>(x, R, g0, wp);
        histF_kernel<<<2048, 256, 0, stream>>>(R, g0, fine, mm);
        build_coarse_kernel<<<1024, 256, 0, stream>>>(fine, coarse);
        nms_kernel<<<sgrid, 256, 0, stream>>>(R, g0, nullptr, nullptr,
                                              coarse, fine, mm, 1, out);
    } else {
        // fallback: round-9 3-pass layout g0 | g1[2x4096] | g2[2x256]
        unsigned* g1 = g0 + 4096;
        unsigned* g2 = g1 + 8192;
        init_kernel<<<64, 256, 0, stream>>>(g0, 12800u, nullptr, 0);
        harris_kernel<<<sgrid, 256, 0, stream>>>(x, R, g0, wp);
        hist1_kernel<<<HBLK, 256, 0, stream>>>(R, g0, g1);
        hist2_kernel<<<HBLK, 256, 0, stream>>>(R, g0, g1, g2);
        nms_kernel<<<sgrid, 256, 0, stream>>>(R, g0, g1, g2,
                                              nullptr, nullptr, nullptr, 0, out);
    }
}

// Round 13
// 250.799 us; speedup vs baseline: 1.2620x; 1.0457x over previous
//
#include <hip/hip_runtime.h>
#include <math.h>

#define N_IMG 4096
#define NBC   1024        // cols per block (256 threads x 4 cols)
#define H_OUT 32          // harris output rows per block
#define HR    38          // H_OUT + 6 halo
#define NMS_HOUT 16       // nms output rows per block -> 1024 blocks = 4/CU (TLP)
#define NMS_HR   22       // NMS_HOUT + 6 halo
#define NPIX  (N_IMG * N_IMG)
#define HBLK  1024        // fallback hist kernel grid (round-9 proven)
#define FINE_WORDS (1u << 20)

struct W7 { float w[7]; };

__device__ __forceinline__ unsigned f2k(float f) {
    unsigned u = __float_as_uint(f);
    return (u & 0x80000000u) ? ~u : (u | 0x80000000u);
}
__device__ __forceinline__ float k2f(unsigned k) {
    unsigned u = (k & 0x80000000u) ? (k & 0x7fffffffu) : ~k;
    return __uint_as_float(u);
}

// ---------- per-block radix-select re-derivation (no fences, no gates) ----------
struct SelState { unsigned p1, p2, r1, r2; };

template<int BINS>
__device__ void locate_pair(const unsigned* h0, const unsigned* h1,
                            int shift, SelState& s)
{
    __shared__ unsigned scan[256];
    __shared__ unsigned resb[2], resr[2];
    const int tid = threadIdx.x;
    const int per = BINS / 256;
    const bool same = (h0 == h1);

    for (int q = 0; q < 2; q++) {
        if (q == 1 && same) break;
        const unsigned* h = q ? h1 : h0;
        const int base = tid * per;
        unsigned sum = 0;
        #pragma unroll
        for (int i = 0; i < per; i++) sum += h[base + i];
        __syncthreads();                  // protect scan[] reuse across calls
        scan[tid] = sum;
        __syncthreads();
        unsigned v = sum;
        #pragma unroll
        for (int off = 1; off < 256; off <<= 1) {
            unsigned t = (tid >= off) ? scan[tid - off] : 0u;
            __syncthreads();
            v += t;
            scan[tid] = v;
            __syncthreads();
        }
        const unsigned excl = v - sum;
        #pragma unroll
        for (int w = 0; w < 2; w++) {
            const unsigned rank = w ? s.r2 : s.r1;
            const bool mine = w ? (same || q == 1) : (q == 0);
            if (mine && rank >= excl && rank < v) {
                unsigned rr = rank - excl;
                for (int i = 0; i < per; i++) {
                    unsigned c = h[base + i];
                    if (rr < c) { resb[w] = (unsigned)(base + i); resr[w] = rr; break; }
                    rr -= c;
                }
            }
        }
        __syncthreads();
    }
    s.p1 |= resb[0] << shift; s.r1 = resr[0];
    s.p2 |= resb[1] << shift; s.r2 = resr[1];
}

__device__ __forceinline__ SelState derive0(const unsigned* g0) {
    SelState s; s.p1 = 0u; s.p2 = 0u;
    s.r1 = (unsigned)(NPIX / 2 - 1); s.r2 = (unsigned)(NPIX / 2);
    locate_pair<4096>(g0, g0, 20, s);
    return s;
}
// fallback (3-pass) derives
__device__ __forceinline__ void derive1(const unsigned* g1, SelState& s) {
    const unsigned* h1 = (s.p1 != s.p2) ? (g1 + 4096) : g1;
    locate_pair<4096>(g1, h1, 8, s);
}
__device__ __forceinline__ void derive2(const unsigned* g2, SelState& s) {
    const unsigned* h1 = (s.p1 != s.p2) ? (g2 + 256) : g2;
    locate_pair<256>(g2, h1, 0, s);
}
// fine-path derives (verified rounds 6/12): coarse = bits 19:8, fine window = bits 7:0
__device__ __forceinline__ void derive_coarse(const unsigned* coarse, SelState& s) {
    locate_pair<4096>(coarse, coarse, 8, s);
}
__device__ __forceinline__ void derive_fine(const unsigned* fine, SelState& s) {
    const unsigned* f1 = fine + (((s.p1 >> 8) & 0xFFFu) << 8);
    const unsigned* f2 = fine + (((s.p2 >> 8) & 0xFFFu) << 8);
    locate_pair<256>(f1, f2, 0, s);
}

// ---------- harris (EXACT round-12 body: scatter-acc + depth-1 prefetch) ----------
__global__ __launch_bounds__(256, 2) void harris_kernel(const float* __restrict__ x,
                                                        float* __restrict__ R,
                                                        unsigned* __restrict__ g0,
                                                        W7 wp)
{
    __shared__ unsigned histo[4096];
    const int tid = threadIdx.x;
    for (int i = tid; i < 4096; i += 256) histo[i] = 0;
    __syncthreads();

    const int row0 = blockIdx.y * H_OUT;
    const int jc   = blockIdx.x * NBC + tid * 4;   // first owned column
    const float* w = wp.w;
    const bool edge = (jc < 4) || (jc >= N_IMG - 8);   // lanes needing col clamps

    float xm[12], xc[12], xp[12], xn[12];          // rolling x rows (cols jc-4..jc+7)
    float axx[7][4], ayy[7][4], axy[7][4];         // 7 pending vertical accumulators

    #pragma unroll
    for (int m = 0; m < 7; m++)
        #pragma unroll
        for (int o = 0; o < 4; o++) { axx[m][o] = 0.f; ayy[m][o] = 0.f; axy[m][o] = 0.f; }

    auto loadrow = [&](int ri, float* d) {
        if ((unsigned)ri < N_IMG) {
            const float* p = x + (size_t)ri * N_IMG;
            float4 v0 = make_float4(0.f,0.f,0.f,0.f), v2 = make_float4(0.f,0.f,0.f,0.f);
            if (jc >= 4) v0 = *(const float4*)(p + jc - 4);
            float4 v1 = *(const float4*)(p + jc);
            if (jc + 4 < N_IMG) v2 = *(const float4*)(p + jc + 4);
            d[0]=v0.x; d[1]=v0.y; d[2]=v0.z; d[3]=v0.w;
            d[4]=v1.x; d[5]=v1.y; d[6]=v1.z; d[7]=v1.w;
            d[8]=v2.x; d[9]=v2.y; d[10]=v2.z; d[11]=v2.w;
        } else {
            #pragma unroll
            for (int t = 0; t < 12; t++) d[t] = 0.f;
        }
    };

    loadrow(row0 - 4, xm);
    loadrow(row0 - 3, xc);
    loadrow(row0 - 2, xp);

    int curb = -1; unsigned cnt = 0;   // histogram run-length state

    auto step = [&](int r, int k, int dmin, bool emit) {
        const int ri = row0 + r - 3;   // image row of this h row
        loadrow(ri + 2, xn);           // PREFETCH: consumed next step (becomes xp)

        if ((unsigned)ri < N_IMG) {
            float dc[12], rd[12];
            #pragma unroll
            for (int t = 0; t < 12; t++) {
                dc[t] = xm[t] + 2.f * xc[t] + xp[t];
                rd[t] = xp[t] - xm[t];
            }
            float ixv[10], iyv[10];
            #pragma unroll
            for (int t = 0; t < 10; t++) {
                ixv[t] = dc[t+2] - dc[t];
                iyv[t] = rd[t] + 2.f * rd[t+1] + rd[t+2];
            }
            if (edge) {                 // execz-skipped by interior waves
                #pragma unroll
                for (int t = 0; t < 10; t++)
                    if ((unsigned)(jc - 3 + t) >= N_IMG) { ixv[t] = 0.f; iyv[t] = 0.f; }
            }
            float sxx[4] = {0,0,0,0}, syy[4] = {0,0,0,0}, sxy[4] = {0,0,0,0};
            #pragma unroll
            for (int t = 0; t < 10; t++) {
                float ix = ixv[t], iy = iyv[t];
                float xx = ix*ix, yy = iy*iy, xy = ix*iy;
                #pragma unroll
                for (int o = 0; o < 4; o++) {
                    const int v = t - o;
                    if (v >= 0 && v < 7) {
                        sxx[o] = fmaf(w[v], xx, sxx[o]);
                        syy[o] = fmaf(w[v], yy, syy[o]);
                        sxy[o] = fmaf(w[v], xy, sxy[o]);
                    }
                }
            }
            #pragma unroll
            for (int d = 0; d < 7; d++) {
                if (d >= dmin) {
                    const int m = (k + d) % 7;   // static after unroll
                    #pragma unroll
                    for (int o = 0; o < 4; o++) {
                        axx[m][o] = fmaf(w[6-d], sxx[o], axx[m][o]);
                        ayy[m][o] = fmaf(w[6-d], syy[o], ayy[m][o]);
                        axy[m][o] = fmaf(w[6-d], sxy[o], axy[m][o]);
                    }
                }
            }
        }

        if (emit) {                     // output q == r completes in slot k
            float4 h;
            float* hp = &h.x;
            #pragma unroll
            for (int o = 0; o < 4; o++) {
                float ax = axx[k][o], ay = ayy[k][o], az = axy[k][o];
                axx[k][o] = 0.f; ayy[k][o] = 0.f; axy[k][o] = 0.f;
                float tr = ax + ay;
                hp[o] = ax*ay - az*az - 0.05f*tr*tr;
            }
            const int orow = row0 + r - 6;
            *(float4*)(R + (size_t)orow * N_IMG + jc) = h;
            #pragma unroll
            for (int o = 0; o < 4; o++) {
                int b = (int)(f2k(hp[o]) >> 20);
                if (b == curb) cnt++;
                else { if (curb >= 0) atomicAdd(&histo[curb], cnt); curb = b; cnt = 1; }
            }
        }
        #pragma unroll
        for (int t = 0; t < 12; t++) { xm[t] = xc[t]; xc[t] = xp[t]; xp[t] = xn[t]; }
    };

    #pragma unroll
    for (int rr = 0; rr < 7; ++rr)
        step(rr, rr, 6 - rr, rr == 6);
    for (int it = 1; it < 6; ++it) {
        #pragma unroll
        for (int k = 0; k < 7; ++k) {
            const int r = it * 7 + k;
            if (r < HR) step(r, k, 0, true);
        }
    }

    if (curb >= 0) atomicAdd(&histo[curb], cnt);
    __syncthreads();
    for (int i = tid; i < 4096; i += 256) {
        unsigned c = histo[i];
        if (c) atomicAdd(&g0[i], c);
    }
}

// ---------- FINE PATH (EXACT round-12): one R scan resolving 20 bits ----------
__global__ __launch_bounds__(256) void histF_kernel(const float* __restrict__ R,
                                                    const unsigned* __restrict__ g0,
                                                    unsigned* __restrict__ fine,
                                                    unsigned* __restrict__ mm)
{
    __shared__ unsigned rmax[256], rmin[256];
    SelState s = derive0(g0);
    const unsigned p1 = s.p1, p2 = s.p2;
    const bool dual = (p1 != p2);
    const unsigned mask = 0xFFF00000u;
    const int tid = threadIdx.x;
    const int n4 = NPIX / 4;
    const float4* R4 = (const float4*)R;

    if (!dual) {
        unsigned curlo = 0xFFFFFFFFu; unsigned cnt = 0;
        for (int i = blockIdx.x * 256 + tid; i < n4; i += gridDim.x * 256) {
            float4 v = R4[i];
            float vv[4] = {v.x, v.y, v.z, v.w};
            #pragma unroll
            for (int t = 0; t < 4; t++) {
                unsigned k = f2k(vv[t]);
                if ((k & mask) == p1) {
                    unsigned lo = k & 0xFFFFFu;
                    if (lo == curlo) cnt++;
                    else { if (cnt) atomicAdd(&fine[curlo], cnt); curlo = lo; cnt = 1; }
                }
            }
        }
        if (cnt) atomicAdd(&fine[curlo], cnt);
    } else {
        unsigned bmax = 0u, bmin = 0xFFFFFFFFu;
        for (int i = blockIdx.x * 256 + tid; i < n4; i += gridDim.x * 256) {
            float4 v = R4[i];
            float vv[4] = {v.x, v.y, v.z, v.w};
            #pragma unroll
            for (int t = 0; t < 4; t++) {
                unsigned k = f2k(vv[t]);
                if ((k & mask) == p1) bmax = max(bmax, k);
                if ((k & mask) == p2) bmin = min(bmin, k);
            }
        }
        rmax[tid] = bmax; rmin[tid] = bmin;
        __syncthreads();
        for (int off = 128; off; off >>= 1) {
            if (tid < off) {
                rmax[tid] = max(rmax[tid], rmax[tid + off]);
                rmin[tid] = min(rmin[tid], rmin[tid + off]);
            }
            __syncthreads();
        }
        if (tid == 0) { atomicMax(&mm[0], rmax[0]); atomicMin(&mm[1], rmin[0]); }
    }
}

// coarse[c] = sum of fine[c*256 .. c*256+255]; one wave per bin, no atomics
__global__ __launch_bounds__(256) void build_coarse_kernel(const unsigned* __restrict__ fine,
                                                           unsigned* __restrict__ coarse)
{
    const int tid = threadIdx.x;
    const int wave = tid >> 6, lane = tid & 63;
    const int c = blockIdx.x * 4 + wave;          // 1024 blocks x 4 waves = 4096 bins
    const uint4* f4 = (const uint4*)(fine + (size_t)c * 256);
    uint4 v = f4[lane];
    unsigned sm = v.x + v.y + v.z + v.w;
    #pragma unroll
    for (int off = 32; off; off >>= 1) sm += __shfl_down(sm, off);
    if (lane == 0) coarse[c] = sm;
}

// ---------- FALLBACK PATH (round-9 exact): 3-pass LDS radix ----------
__global__ __launch_bounds__(256) void hist1_kernel(const float* __restrict__ R,
                                                    const unsigned* __restrict__ g0,
                                                    unsigned* __restrict__ g1)
{
    __shared__ unsigned h[2][4096];
    const int tid = threadIdx.x;
    for (int i = tid; i < 8192; i += 256) ((unsigned*)h)[i] = 0u;

    SelState s = derive0(g0);
    const unsigned p1 = s.p1, p2 = s.p2;
    const bool dual = (p1 != p2);
    const unsigned mask = 0xFFF00000u;
    const int shift = 8;

    const int n4 = NPIX / 4;
    const int stride = gridDim.x * 256;
    int curb1 = -1; unsigned cnt1 = 0;
    int curb2 = -1; unsigned cnt2 = 0;
    const float4* R4 = (const float4*)R;

    auto proc = [&](unsigned k) {
        if ((k & mask) == p1) {
            int b = (int)((k >> shift) & 4095u);
            if (b == curb1) cnt1++;
            else { if (cnt1) atomicAdd(&h[0][curb1], cnt1); curb1 = b; cnt1 = 1; }
        }
        if (dual && (k & mask) == p2) {
            int b = (int)((k >> shift) & 4095u);
            if (b == curb2) cnt2++;
            else { if (cnt2) atomicAdd(&h[1][curb2], cnt2); curb2 = b; cnt2 = 1; }
        }
    };

    int i = blockIdx.x * 256 + tid;
    for (; i + 3 * stride < n4; i += 4 * stride) {
        float4 va = R4[i];
        float4 vb = R4[i + stride];
        float4 vc = R4[i + 2 * stride];
        float4 vd = R4[i + 3 * stride];
        float vv[16] = {va.x, va.y, va.z, va.w, vb.x, vb.y, vb.z, vb.w,
                        vc.x, vc.y, vc.z, vc.w, vd.x, vd.y, vd.z, vd.w};
        #pragma unroll
        for (int t = 0; t < 16; t++) proc(f2k(vv[t]));
    }
    for (; i < n4; i += stride) {
        float4 va = R4[i];
        float vv[4] = {va.x, va.y, va.z, va.w};
        #pragma unroll
        for (int t = 0; t < 4; t++) proc(f2k(vv[t]));
    }
    if (cnt1) atomicAdd(&h[0][curb1], cnt1);
    if (cnt2) atomicAdd(&h[1][curb2], cnt2);
    __syncthreads();
    for (int j = tid; j < 4096; j += 256) {
        unsigned c0 = h[0][j]; if (c0) atomicAdd(&g1[j], c0);
        if (dual) { unsigned c1 = h[1][j]; if (c1) atomicAdd(&g1[4096 + j], c1); }
    }
}

__global__ __launch_bounds__(256) void hist2_kernel(const float* __restrict__ R,
                                                    const unsigned* __restrict__ g0,
                                                    const unsigned* __restrict__ g1,
                                                    unsigned* __restrict__ g2)
{
    __shared__ unsigned h[2][256];
    const int tid = threadIdx.x;
    for (int i = tid; i < 512; i += 256) ((unsigned*)h)[i] = 0u;

    SelState s = derive0(g0);
    derive1(g1, s);
    const unsigned p1 = s.p1, p2 = s.p2;
    const bool dual = (p1 != p2);
    const unsigned mask = 0xFFFFFF00u;

    const int n4 = NPIX / 4;
    const int stride = gridDim.x * 256;
    int curb1 = -1; unsigned cnt1 = 0;
    int curb2 = -1; unsigned cnt2 = 0;
    const float4* R4 = (const float4*)R;

    auto proc = [&](unsigned k) {
        if ((k & mask) == p1) {
            int b = (int)(k & 255u);
            if (b == curb1) cnt1++;
            else { if (cnt1) atomicAdd(&h[0][curb1], cnt1); curb1 = b; cnt1 = 1; }
        }
        if (dual && (k & mask) == p2) {
            int b = (int)(k & 255u);
            if (b == curb2) cnt2++;
            else { if (cnt2) atomicAdd(&h[1][curb2], cnt2); curb2 = b; cnt2 = 1; }
        }
    };

    int i = blockIdx.x * 256 + tid;
    for (; i + 3 * stride < n4; i += 4 * stride) {
        float4 va = R4[i];
        float4 vb = R4[i + stride];
        float4 vc = R4[i + 2 * stride];
        float4 vd = R4[i + 3 * stride];
        float vv[16] = {va.x, va.y, va.z, va.w, vb.x, vb.y, vb.z, vb.w,
                        vc.x, vc.y, vc.z, vc.w, vd.x, vd.y, vd.z, vd.w};
        #pragma unroll
        for (int t = 0; t < 16; t++) proc(f2k(vv[t]));
    }
    for (; i < n4; i += stride) {
        float4 va = R4[i];
        float vv[4] = {va.x, va.y, va.z, va.w};
        #pragma unroll
        for (int t = 0; t < 4; t++) proc(f2k(vv[t]));
    }
    if (cnt1) atomicAdd(&h[0][curb1], cnt1);
    if (cnt2) atomicAdd(&h[1][curb2], cnt2);
    __syncthreads();
    if (tid < 256) {
        unsigned c0 = h[0][tid]; if (c0) atomicAdd(&g2[tid], c0);
        if (dual) { unsigned c1 = h[1][tid]; if (c1) atomicAdd(&g2[256 + tid], c1); }
    }
}

// zero nwords at g; set mm sentinels in fine mode
__global__ __launch_bounds__(256) void init_kernel(unsigned* __restrict__ g,
                                                   unsigned nwords,
                                                   unsigned* __restrict__ mm,
                                                   int fine_mode)
{
    for (unsigned i = blockIdx.x * 256u + threadIdx.x; i < nwords; i += gridDim.x * 256u)
        g[i] = 0u;
    if (fine_mode && blockIdx.x == 0 && threadIdx.x == 0) {
        mm[0] = 0u; mm[1] = 0xFFFFFFFFu;
    }
}

// ---------- NMS (round-12 body; ONLY change: NMS_HOUT=16 -> 1024 blocks, 4/CU) ----------
__global__ __launch_bounds__(256, 4) void nms_kernel(const float* __restrict__ R,
                                                     const unsigned* __restrict__ g0,
                                                     const unsigned* __restrict__ g1,
                                                     const unsigned* __restrict__ g2,
                                                     const unsigned* __restrict__ coarse,
                                                     const unsigned* __restrict__ fine,
                                                     const unsigned* __restrict__ mm,
                                                     int mode,
                                                     float* __restrict__ out)
{
    const int tid  = threadIdx.x;

    SelState s = derive0(g0);
    float med;
    if (mode == 1) {
        if (s.p1 != s.p2) {
            med = 0.5f * (k2f(mm[0]) + k2f(mm[1]));
        } else {
            derive_coarse(coarse, s);
            derive_fine(fine, s);
            med = 0.5f * (k2f(s.p1) + k2f(s.p2));
        }
    } else {
        derive1(g1, s);
        derive2(g2, s);
        med = 0.5f * (k2f(s.p1) + k2f(s.p2));
    }

    const int row0 = blockIdx.y * NMS_HOUT;
    const int jc   = blockIdx.x * NBC + tid * 4;

    float vm[7][4];                    // 7 pending vertical-max accumulators
    float ct[7][4];                    // center-value ring
    #pragma unroll
    for (int m = 0; m < 7; m++)
        #pragma unroll
        for (int o = 0; o < 4; o++) vm[m][o] = -INFINITY;

    auto loadrowT = [&](int ri, float* d) {
        if ((unsigned)ri < N_IMG) {
            const float* p = R + (size_t)ri * N_IMG;
            float4 v1 = *(const float4*)(p + jc);
            d[4] = (v1.x >= med) ? v1.x : 0.f;
            d[5] = (v1.y >= med) ? v1.y : 0.f;
            d[6] = (v1.z >= med) ? v1.z : 0.f;
            d[7] = (v1.w >= med) ? v1.w : 0.f;
            if (jc >= 4) {
                float4 v0 = *(const float4*)(p + jc - 4);
                d[0] = (v0.x >= med) ? v0.x : 0.f;
                d[1] = (v0.y >= med) ? v0.y : 0.f;
                d[2] = (v0.z >= med) ? v0.z : 0.f;
                d[3] = (v0.w >= med) ? v0.w : 0.f;
            } else { d[0]=d[1]=d[2]=d[3] = -INFINITY; }
            if (jc + 4 < N_IMG) {
                float4 v2 = *(const float4*)(p + jc + 4);
                d[8]  = (v2.x >= med) ? v2.x : 0.f;
                d[9]  = (v2.y >= med) ? v2.y : 0.f;
                d[10] = (v2.z >= med) ? v2.z : 0.f;
                d[11] = (v2.w >= med) ? v2.w : 0.f;
            } else { d[8]=d[9]=d[10]=d[11] = -INFINITY; }
        } else {
            #pragma unroll
            for (int t = 0; t < 12; t++) d[t] = -INFINITY;
        }
    };

    auto stepn = [&](int r, int k, int dmin, bool emit) {
        const int ri = row0 + r - 3;
        float a[12];
        loadrowT(ri, a);
        float hm[4];
        #pragma unroll
        for (int o = 0; o < 4; o++) {
            float m01 = fmaxf(a[o+1], a[o+2]);
            float m23 = fmaxf(a[o+3], a[o+4]);
            float m45 = fmaxf(a[o+5], a[o+6]);
            hm[o] = fmaxf(fmaxf(m01, m23), fmaxf(m45, a[o+7]));
            ct[k][o] = a[4+o];
        }
        #pragma unroll
        for (int d = 0; d < 7; d++) {
            if (d >= dmin) {
                const int m = (k + d) % 7;   // static after unroll
                #pragma unroll
                for (int o = 0; o < 4; o++)
                    vm[m][o] = fmaxf(vm[m][o], hm[o]);
            }
        }
        if (emit) {
            float4 ov;
            float* op = &ov.x;
            #pragma unroll
            for (int o = 0; o < 4; o++) {
                float m = vm[k][o];
                vm[k][o] = -INFINITY;
                float c = ct[(k+4) % 7][o];
                op[o] = (c != m) ? 0.f : m;
            }
            const int orow = row0 + r - 6;
            *(float4*)(out + (size_t)orow * N_IMG + jc) = ov;
        }
    };

    #pragma unroll
    for (int rr = 0; rr < 7; ++rr)
        stepn(rr, rr, 6 - rr, rr == 6);
    for (int it = 1; it < 4; ++it) {
        #pragma unroll
        for (int k = 0; k < 7; ++k) {
            const int r = it * 7 + k;
            if (r < NMS_HR) stepn(r, k, 0, true);
        }
    }
}

extern "C" void kernel_launch(void* const* d_in, const int* in_sizes, int n_in,
                              void* d_out, int out_size, void* d_ws, size_t ws_size,
                              hipStream_t stream)
{
    const float* x = (const float*)d_in[0];
    float* R = (float*)d_ws;                                   // 64 MiB
    unsigned* g0 = (unsigned*)((char*)d_ws + (size_t)NPIX * 4);
    float* out = (float*)d_out;

    W7 wp;
    {
        double g[7], sm = 0.0;
        for (int i = 0; i < 7; i++) { double ax = (double)i - 3.0; g[i] = exp(-(ax*ax)/50.0); sm += g[i]; }
        for (int i = 0; i < 7; i++) wp.w[i] = (float)(g[i] / sm);
    }

    dim3 sgrid(N_IMG / NBC, N_IMG / H_OUT);       // (4, 128)
    dim3 ngrid(N_IMG / NBC, N_IMG / NMS_HOUT);    // (4, 256) = 1024 blocks

    // fine layout: g0[4096] | coarse[4096] | mm+pad[64] | fine[1M]
    const unsigned fine_words = 4096u + 4096u + 64u + FINE_WORDS;
    const size_t need_fine = (size_t)NPIX * 4 + (size_t)fine_words * 4;

    if (ws_size >= need_fine) {
        unsigned* coarse = g0 + 4096;
        unsigned* mm     = coarse + 4096;
        unsigned* fine   = mm + 64;
        init_kernel<<<1024, 256, 0, stream>>>(g0, fine_words, mm, 1);
        harris_kernel<<<sgrid, 256, 0, stream>>>(x, R, g0, wp);
        histF_kernel<<<2048, 256, 0, stream>>>(R, g0, fine, mm);
        build_coarse_kernel<<<1024, 256, 0, stream>>>(fine, coarse);
        nms_kernel<<<ngrid, 256, 0, stream>>>(R, g0, nullptr, nullptr,
                                              coarse, fine, mm, 1, out);
    } else {
        // fallback: round-9 3-pass layout g0 | g1[2x4096] | g2[2x256]
        unsigned* g1 = g0 + 4096;
        unsigned* g2 = g1 + 8192;
        init_kernel<<<64, 256, 0, stream>>>(g0, 12800u, nullptr, 0);
        harris_kernel<<<sgrid, 256, 0, stream>>>(x, R, g0, wp);
        hist1_kernel<<<HBLK, 256, 0, stream>>>(R, g0, g1);
        hist2_kernel<<<HBLK, 256, 0, stream>>>(R, g0, g1, g2);
        nms_kernel<<<ngrid, 256, 0, stream>>>(R, g0, g1, g2,
                                              nullptr, nullptr, nullptr, 0, out);
    }
}